// Round 3
// baseline (198.308 us; speedup 1.0000x reference)
//
#include <hip/hip_runtime.h>
#include <stdint.h>

// Problem constants (match reference)
constexpr int BB      = 4;
constexpr int NN      = 8192;
constexpr int NPOINT  = 2048;
constexpr int CC      = 64;
constexpr int NSAMPLE = 32;
constexpr int KTOT    = NSAMPLE + 1;   // fps_idx prepended -> 33
constexpr int NCH     = 3 + 3 + CC;    // 70 output channels

// ---------------------------------------------------------------------------
// Kernel 0: transpose xyz (B,N,3) -> SoA planes (B,3,N) so ball_query loads
// are perfectly coalesced. SoA lives in the head of d_out (gather overwrites
// d_out afterwards, stream-ordered) to avoid relying on ws_size.
// ---------------------------------------------------------------------------
__global__ __launch_bounds__(256) void soa_kernel(
    const float* __restrict__ xyz,   // (B, N, 3)
    float*       __restrict__ soa)   // (B, 3, N)
{
    const int t = blockIdx.x * 256 + threadIdx.x;
    if (t >= BB * NN) return;
    const int b = t >> 13;            // / NN
    const int n = t & (NN - 1);
    const float* p = xyz + (size_t)t * 3;
    float* sb = soa + (size_t)b * 3 * NN;
    sb[n]          = p[0];
    sb[NN + n]     = p[1];
    sb[2 * NN + n] = p[2];
}

// ---------------------------------------------------------------------------
// Kernel 1: ball query. One wave per centroid. Scans points 64 at a time in
// ascending order; ballot + mbcnt prefix assigns in-order slots for the first
// NSAMPLE in-radius indices; pad with first hit (0 if empty); slot 0=fps_idx.
// Early-exit coarsened to every 512 points so the unrolled inner body keeps
// 24 independent coalesced loads in flight (round-1 version broke every 64
// points -> no pipelining -> 70 us latency-bound).
// d2 uses __f*_rn (no fma contraction), sum order (dx^2+dy^2)+dz^2, to
// bit-match the numpy fp32 reference at the d2 < r^2 boundary.
// ---------------------------------------------------------------------------
__global__ __launch_bounds__(256) void ball_query_v2(
    const float* __restrict__ soa,      // (B, 3, N)
    const float* __restrict__ new_xyz,  // (B, NPOINT, 3)
    const int*   __restrict__ fps_idx,  // (B, NPOINT)
    int*         __restrict__ idx_out)  // (B*NPOINT, KTOT)
{
    const int wave = (blockIdx.x * blockDim.x + threadIdx.x) >> 6;
    const int lane = threadIdx.x & 63;

    const float* cp = new_xyz + (size_t)wave * 3;
    const float cx = cp[0], cy = cp[1], cz = cp[2];
    const float r2 = __fmul_rn(0.1f, 0.1f);   // fp32(0.1)^2

    const int b = wave >> 11;                 // / NPOINT
    const float* xs = soa + (size_t)b * 3 * NN;
    const float* ys = xs + NN;
    const float* zs = xs + 2 * NN;
    int* out = idx_out + (size_t)wave * KTOT;

    int count = 0;   // wave-uniform
    int first = 0;   // wave-uniform: first in-radius index

    for (int g = 0; g < NN; g += 512) {
#pragma unroll
        for (int c8 = 0; c8 < 8; ++c8) {
            const int base = g + (c8 << 6);
            const int p = base + lane;
            const float dx = __fsub_rn(cx, xs[p]);
            const float dy = __fsub_rn(cy, ys[p]);
            const float dz = __fsub_rn(cz, zs[p]);
            const float d2 = __fadd_rn(__fadd_rn(__fmul_rn(dx, dx), __fmul_rn(dy, dy)),
                                       __fmul_rn(dz, dz));
            const bool valid = d2 < r2;
            const unsigned long long mask = __ballot(valid);
            if (count == 0 && mask != 0ull) {
                first = base + __builtin_ctzll(mask);   // wave-uniform
            }
            const int prefix = __builtin_amdgcn_mbcnt_hi(
                (unsigned)(mask >> 32),
                __builtin_amdgcn_mbcnt_lo((unsigned)mask, 0u));
            const int slot = count + prefix;
            if (valid && slot < NSAMPLE) out[1 + slot] = p;
            count += (int)__popcll(mask);
        }
        if (count >= NSAMPLE) break;   // uniform branch, coarse granularity
    }

    if (count < NSAMPLE) {
        const int pad = (count > 0) ? first : 0;
        if (lane >= count && lane < NSAMPLE) out[1 + lane] = pad;
    }
    if (lane == 0) out[0] = fps_idx[wave];
}

// ---------------------------------------------------------------------------
// Kernel 2: gather + center + concat (unchanged from round 1 so the counter
// delta isolates the ball-query change). One thread per output element;
// stores fully coalesced; scattered feature reads are L2-resident.
// ---------------------------------------------------------------------------
__global__ __launch_bounds__(256) void gather_kernel(
    const float* __restrict__ xyz,       // (B, N, 3)
    const float* __restrict__ new_xyz,   // (B, NPOINT, 3)
    const float* __restrict__ features,  // (B, C, N)
    const int*   __restrict__ idx,       // (B*NPOINT, KTOT)
    float*       __restrict__ out)       // (B, 70, NPOINT, 33)
{
    const long long total = (long long)BB * NCH * NPOINT * KTOT;
    const long long o = (long long)blockIdx.x * blockDim.x + threadIdx.x;
    if (o >= total) return;

    const int s  = (int)(o % KTOT);
    long long t  = o / KTOT;
    const int j  = (int)(t % NPOINT);
    t /= NPOINT;
    const int ch = (int)(t % NCH);
    const int b  = (int)(t / NCH);

    const int id = idx[(long long)(b * NPOINT + j) * KTOT + s];

    float v;
    if (ch < 6) {
        const int c3 = (ch >= 3) ? (ch - 3) : ch;
        const float g = xyz[((long long)b * NN + id) * 3 + c3];
        const float c = new_xyz[((long long)b * NPOINT + j) * 3 + c3];
        v = __fsub_rn(g, c);
    } else {
        v = features[((long long)b * CC + (ch - 6)) * NN + id];
    }
    out[o] = v;
}

extern "C" void kernel_launch(void* const* d_in, const int* in_sizes, int n_in,
                              void* d_out, int out_size, void* d_ws, size_t ws_size,
                              hipStream_t stream) {
    const float* xyz      = (const float*)d_in[0];
    const float* new_xyz  = (const float*)d_in[1];
    const float* features = (const float*)d_in[2];
    const int*   fps_idx  = (const int*)d_in[3];
    float*       out      = (float*)d_out;
    int*         idxbuf   = (int*)d_ws;    // B*NPOINT*KTOT int32 ~= 1.08 MB
    float*       soa      = out;           // 393 KB scratch in head of d_out;
                                           // gather overwrites all of d_out after

    // Stage 0: xyz AoS -> SoA (coalesced ball-query loads).
    soa_kernel<<<(BB * NN + 255) / 256, 256, 0, stream>>>(xyz, soa);

    // Stage 1: ball query. One wave per centroid, 4 waves per block.
    const int nwaves = BB * NPOINT;                 // 8192
    ball_query_v2<<<nwaves / 4, 256, 0, stream>>>(soa, new_xyz, fps_idx, idxbuf);

    // Stage 2: gather/center/concat. One thread per output element.
    const long long total = (long long)BB * NCH * NPOINT * KTOT;  // 18,923,520
    const int blocks = (int)((total + 255) / 256);
    gather_kernel<<<blocks, 256, 0, stream>>>(xyz, new_xyz, features, idxbuf, out);
}

// Round 4
// 137.919 us; speedup vs baseline: 1.4379x; 1.4379x over previous
//
#include <hip/hip_runtime.h>
#include <stdint.h>

// Problem constants (match reference)
constexpr int BB      = 4;
constexpr int NN      = 8192;
constexpr int NPOINT  = 2048;
constexpr int CC      = 64;
constexpr int NSAMPLE = 32;
constexpr int KTOT    = NSAMPLE + 1;   // fps_idx prepended -> 33
constexpr int NCH     = 3 + 3 + CC;    // 70 output channels
constexpr int HALF    = NN / 2;        // 4096 points per LDS pass

// SoA scratch layout (lives in head of d_out, overwritten later by gather):
// xy interleaved float2[B*N] at float-offset 0, z float[B*N] at XY_FLOATS.
constexpr int XY_FLOATS = 2 * BB * NN;   // 65536 floats

// ---------------------------------------------------------------------------
// Kernel 0: xyz AoS (B,N,3) -> xy-pair plane + z plane.
// ---------------------------------------------------------------------------
__global__ __launch_bounds__(256) void soa_kernel(
    const float* __restrict__ xyz, float* __restrict__ soa)
{
    const int t = blockIdx.x * 256 + threadIdx.x;
    if (t >= BB * NN) return;
    const float* p = xyz + (size_t)t * 3;
    ((float2*)soa)[t] = make_float2(p[0], p[1]);
    soa[XY_FLOATS + t] = p[2];
}

// ---------------------------------------------------------------------------
// Kernel 1: ball query v3. 512-thread blocks (8 waves); each wave owns TWO
// centroids (amortizes point reads); the block stages 4096 points (48 KB)
// in LDS per pass, two passes. Slot logic skipped when ballot mask == 0.
// Early exit (both centroids full) checked every 512 points.
// d2 math: __f*_rn, sum order (dx^2+dy^2)+dz^2 — bit-matches numpy fp32.
// ---------------------------------------------------------------------------
__global__ __launch_bounds__(512) void ball_query_v3(
    const float* __restrict__ soa,      // xy plane + z plane
    const float* __restrict__ new_xyz,  // (B, NPOINT, 3)
    const int*   __restrict__ fps_idx,  // (B, NPOINT)
    int*         __restrict__ idx_out)  // (B*NPOINT, KTOT)
{
    __shared__ float lds[HALF * 3];     // xy: [0, 8192) floats, z: [8192, 12288)
    const int widx = threadIdx.x >> 6;       // wave in block, 0..7
    const int lane = threadIdx.x & 63;
    const int w    = blockIdx.x * 8 + widx;  // global wave id, 0..4095
    const int c0   = 2 * w;                  // centroid ids (same batch)
    const int b    = c0 >> 11;               // / NPOINT

    const float* np = new_xyz + (size_t)c0 * 3;
    const float cx0 = np[0], cy0 = np[1], cz0 = np[2];
    const float cx1 = np[3], cy1 = np[4], cz1 = np[5];
    const float r2 = __fmul_rn(0.1f, 0.1f);   // fp32(0.1)^2

    int count0 = 0, count1 = 0, first0 = 0, first1 = 0;
    int* out0 = idx_out + (size_t)c0 * KTOT;
    int* out1 = out0 + KTOT;

    const float2* lxy = (const float2*)lds;
    const float*  lz  = lds + 2 * HALF;

    for (int pass = 0; pass < 2; ++pass) {
        // ---- fill 48 KB: xy = 2048 float4, z = 1024 float4; 512 threads ----
        {
            const int base_pt = b * NN + pass * HALF;
            const float4* gxy = (const float4*)soa + (size_t)base_pt / 2;
            const float4* gz  = (const float4*)(soa + XY_FLOATS + base_pt);
            float4* lxy4 = (float4*)lds;
            float4* lz4  = (float4*)(lds + 2 * HALF);
#pragma unroll
            for (int i = 0; i < 4; ++i)
                lxy4[threadIdx.x + 512 * i] = gxy[threadIdx.x + 512 * i];
#pragma unroll
            for (int i = 0; i < 2; ++i)
                lz4[threadIdx.x + 512 * i] = gz[threadIdx.x + 512 * i];
        }
        __syncthreads();

        if (!(count0 >= NSAMPLE && count1 >= NSAMPLE)) {
            for (int grp = 0; grp < HALF / 512; ++grp) {   // 8 groups of 512
#pragma unroll
                for (int c8 = 0; c8 < 8; ++c8) {
                    const int loc = grp * 512 + c8 * 64 + lane;
                    const float2 xy = lxy[loc];
                    const float  z  = lz[loc];
                    const int p = pass * HALF + loc;       // global point index

                    if (count0 < NSAMPLE) {
                        const float dx = __fsub_rn(cx0, xy.x);
                        const float dy = __fsub_rn(cy0, xy.y);
                        const float dz = __fsub_rn(cz0, z);
                        const float d2 = __fadd_rn(__fadd_rn(__fmul_rn(dx, dx), __fmul_rn(dy, dy)),
                                                   __fmul_rn(dz, dz));
                        const bool v = d2 < r2;
                        const unsigned long long m = __ballot(v);
                        if (m != 0ull) {
                            if (count0 == 0) first0 = (p - lane) + __builtin_ctzll(m);
                            const int slot = count0 + __builtin_amdgcn_mbcnt_hi(
                                (unsigned)(m >> 32), __builtin_amdgcn_mbcnt_lo((unsigned)m, 0u));
                            if (v && slot < NSAMPLE) out0[1 + slot] = p;
                            count0 += (int)__popcll(m);
                        }
                    }
                    if (count1 < NSAMPLE) {
                        const float dx = __fsub_rn(cx1, xy.x);
                        const float dy = __fsub_rn(cy1, xy.y);
                        const float dz = __fsub_rn(cz1, z);
                        const float d2 = __fadd_rn(__fadd_rn(__fmul_rn(dx, dx), __fmul_rn(dy, dy)),
                                                   __fmul_rn(dz, dz));
                        const bool v = d2 < r2;
                        const unsigned long long m = __ballot(v);
                        if (m != 0ull) {
                            if (count1 == 0) first1 = (p - lane) + __builtin_ctzll(m);
                            const int slot = count1 + __builtin_amdgcn_mbcnt_hi(
                                (unsigned)(m >> 32), __builtin_amdgcn_mbcnt_lo((unsigned)m, 0u));
                            if (v && slot < NSAMPLE) out1[1 + slot] = p;
                            count1 += (int)__popcll(m);
                        }
                    }
                }
                if (count0 >= NSAMPLE && count1 >= NSAMPLE) break;
            }
        }
        __syncthreads();   // all waves done reading before next fill
    }

    if (count0 < NSAMPLE) {
        const int pad = (count0 > 0) ? first0 : 0;
        if (lane >= count0 && lane < NSAMPLE) out0[1 + lane] = pad;
    }
    if (count1 < NSAMPLE) {
        const int pad = (count1 > 0) ? first1 : 0;
        if (lane >= count1 && lane < NSAMPLE) out1[1 + lane] = pad;
    }
    if (lane == 0) { out0[0] = fps_idx[c0]; out1[0] = fps_idx[c0 + 1]; }
}

// ---------------------------------------------------------------------------
// Kernel 2a: features (B,C,N) -> ft (B,N,C), LDS-tiled 64x64.
// ---------------------------------------------------------------------------
__global__ __launch_bounds__(256) void feat_transpose(
    const float* __restrict__ f, float* __restrict__ ft)
{
    __shared__ float tile[64 * 65];
    const int blk = blockIdx.x;          // B * (N/64) = 512
    const int b   = blk >> 7;
    const int n0  = (blk & 127) << 6;
    const int w   = threadIdx.x >> 6, l = threadIdx.x & 63;
#pragma unroll
    for (int i = 0; i < 16; ++i) {
        const int c = i * 4 + w;
        tile[l * 65 + c] = f[((size_t)b * CC + c) * NN + n0 + l];  // coalesced read
    }
    __syncthreads();
#pragma unroll
    for (int i = 0; i < 16; ++i) {
        const int flat = i * 256 + threadIdx.x;                    // n*64 + c
        ft[((size_t)b * NN + n0) * CC + flat] = tile[(flat >> 6) * 65 + (flat & 63)];
    }
}

// ---------------------------------------------------------------------------
// Kernel 2b: gather v3. One thread per (b, j, s): reads its id's 64 channels
// as 16 float4 loads from ft (full cacheline utilization via L1 across the
// loop) and writes all 70 channel outputs; every store is coalesced across
// lanes (consecutive lanes = consecutive j*33+s).
// ---------------------------------------------------------------------------
__global__ __launch_bounds__(256) void gather_v3(
    const float* __restrict__ xyz, const float* __restrict__ new_xyz,
    const float* __restrict__ ft, const int* __restrict__ idx,
    float* __restrict__ out)
{
    const int o = blockIdx.x * 256 + threadIdx.x;
    if (o >= BB * NPOINT * KTOT) return;
    const int s = o % KTOT;
    const int t = o / KTOT;
    const int j = t & (NPOINT - 1);
    const int b = t >> 11;
    const int id = idx[o];

    const size_t chstride = (size_t)NPOINT * KTOT;
    const size_t outb = (size_t)b * NCH * chstride + (size_t)j * KTOT + s;

    const float* gp = xyz + ((size_t)b * NN + id) * 3;
    const float* cp = new_xyz + ((size_t)b * NPOINT + j) * 3;
    const float vx = __fsub_rn(gp[0], cp[0]);
    const float vy = __fsub_rn(gp[1], cp[1]);
    const float vz = __fsub_rn(gp[2], cp[2]);
    out[outb]                = vx;
    out[outb + chstride]     = vy;
    out[outb + 2 * chstride] = vz;
    out[outb + 3 * chstride] = vx;
    out[outb + 4 * chstride] = vy;
    out[outb + 5 * chstride] = vz;

    const float4* fp = (const float4*)ft + ((size_t)b * NN + id) * (CC / 4);
#pragma unroll
    for (int q = 0; q < CC / 4; ++q) {
        const float4 v = fp[q];
        const size_t base = outb + (size_t)(6 + 4 * q) * chstride;
        out[base]                = v.x;
        out[base + chstride]     = v.y;
        out[base + 2 * chstride] = v.z;
        out[base + 3 * chstride] = v.w;
    }
}

// Fallback gather (round-2 version) if ws_size can't hold ft.
__global__ __launch_bounds__(256) void gather_kernel(
    const float* __restrict__ xyz, const float* __restrict__ new_xyz,
    const float* __restrict__ features, const int* __restrict__ idx,
    float* __restrict__ out)
{
    const long long total = (long long)BB * NCH * NPOINT * KTOT;
    const long long o = (long long)blockIdx.x * blockDim.x + threadIdx.x;
    if (o >= total) return;
    const int s  = (int)(o % KTOT);
    long long t  = o / KTOT;
    const int j  = (int)(t % NPOINT);
    t /= NPOINT;
    const int ch = (int)(t % NCH);
    const int b  = (int)(t / NCH);
    const int id = idx[(long long)(b * NPOINT + j) * KTOT + s];
    float v;
    if (ch < 6) {
        const int c3 = (ch >= 3) ? (ch - 3) : ch;
        v = __fsub_rn(xyz[((long long)b * NN + id) * 3 + c3],
                      new_xyz[((long long)b * NPOINT + j) * 3 + c3]);
    } else {
        v = features[((long long)b * CC + (ch - 6)) * NN + id];
    }
    out[o] = v;
}

extern "C" void kernel_launch(void* const* d_in, const int* in_sizes, int n_in,
                              void* d_out, int out_size, void* d_ws, size_t ws_size,
                              hipStream_t stream) {
    const float* xyz      = (const float*)d_in[0];
    const float* new_xyz  = (const float*)d_in[1];
    const float* features = (const float*)d_in[2];
    const int*   fps_idx  = (const int*)d_in[3];
    float*       out      = (float*)d_out;

    int*  idxbuf = (int*)d_ws;
    const size_t idx_bytes = (size_t)BB * NPOINT * KTOT * 4;   // 1,081,344 (16-aligned)
    const size_t ft_bytes  = (size_t)BB * NN * CC * 4;         // 8,388,608
    float* soa = out;   // 384 KB in head of d_out; gather overwrites all of out after

    // Stage 0: xyz AoS -> SoA planes.
    soa_kernel<<<(BB * NN + 255) / 256, 256, 0, stream>>>(xyz, soa);

    // Stage 1: ball query (LDS-staged, 2 centroids/wave).
    ball_query_v3<<<512, 512, 0, stream>>>(soa, new_xyz, fps_idx, idxbuf);

    // Stage 2: gather. Fast path needs ft scratch in ws.
    const int gblocks = (BB * NPOINT * KTOT + 255) / 256;
    if (ws_size >= idx_bytes + ft_bytes) {
        float* ft = (float*)((char*)d_ws + idx_bytes);
        feat_transpose<<<BB * (NN / 64), 256, 0, stream>>>(features, ft);
        gather_v3<<<gblocks, 256, 0, stream>>>(xyz, new_xyz, ft, idxbuf, out);
    } else {
        const long long total = (long long)BB * NCH * NPOINT * KTOT;
        gather_kernel<<<(int)((total + 255) / 256), 256, 0, stream>>>(
            xyz, new_xyz, features, idxbuf, out);
    }
}